// Round 6
// baseline (114.677 us; speedup 1.0000x reference)
//
#include <hip/hip_runtime.h>

#define B_ 256
#define H_ 512
#define KF 256
#define BH 131072    // B_*H_
#define BH2 65536    // BH/2
#define BH4 32768    // BH/4
#define H4 128       // H_/4

#define BM 64
#define BN 64
#define BK 16

__device__ __forceinline__ float sigmoidf_(float x) { return 1.0f / (1.0f + __expf(-x)); }
__device__ __forceinline__ float tanh_fast(float x) { return 2.0f / (1.0f + __expf(-2.0f * x)) - 1.0f; }
__device__ __forceinline__ float4 sig4(float4 v) {
    return make_float4(sigmoidf_(v.x), sigmoidf_(v.y), sigmoidf_(v.z), sigmoidf_(v.w));
}

#define MAC_LOOP()                                                         \
    _Pragma("unroll")                                                      \
    for (int kk = 0; kk < BK; ++kk) {                                      \
        const float4 a = *(const float4*)&As[kk][ty << 2];                 \
        const float4 w = *(const float4*)&Ws[kk][tx << 2];                 \
        const float a4[4] = {a.x, a.y, a.z, a.w};                          \
        const float w4[4] = {w.x, w.y, w.z, w.w};                          \
        _Pragma("unroll")                                                  \
        for (int i = 0; i < 4; ++i)                                        \
            _Pragma("unroll")                                              \
            for (int j = 0; j < 4; ++j)                                    \
                acc[i][j] = fmaf(a4[i], w4[j], acc[i][j]);                 \
    }

// ---------------------------------------------------------------------------
// 64x64-tile split-K partial GEMM over a K-chunk, register double-stage.
// ---------------------------------------------------------------------------
template<bool MUL>
__device__ __forceinline__ void gemm64(
    float (*As)[BM + 4], float (*Ws)[BN + 4],
    const float* __restrict__ abase, const float* __restrict__ rbase,
    const float* __restrict__ W, int Ktot, int ks,
    int bm, int bn, int nIter, float* __restrict__ p)
{
    const int tid = threadIdx.x;
    const int ty = tid >> 4, tx = tid & 15;
    const int lrow = tid >> 2, lcol = (tid & 3) << 2;
    const float* aptr = abase + (bm + lrow) * 512 + lcol;
    const float* rptr = MUL ? rbase + (bm + lrow) * 512 + lcol : nullptr;
    const float* wptr = W + (size_t)(bn + lrow) * Ktot + ks + lcol;

    float acc[4][4] = {};
    float4 av = *(const float4*)aptr;
    if (MUL) { const float4 rv = *(const float4*)rptr;
               av.x *= rv.x; av.y *= rv.y; av.z *= rv.z; av.w *= rv.w; }
    float4 wv = *(const float4*)wptr;

    for (int it = 0; it < nIter; ++it) {
        __syncthreads();
        As[lcol + 0][lrow] = av.x; As[lcol + 1][lrow] = av.y;
        As[lcol + 2][lrow] = av.z; As[lcol + 3][lrow] = av.w;
        Ws[lcol + 0][lrow] = wv.x; Ws[lcol + 1][lrow] = wv.y;
        Ws[lcol + 2][lrow] = wv.z; Ws[lcol + 3][lrow] = wv.w;
        __syncthreads();
        if (it < nIter - 1) {
            av = *(const float4*)(aptr + (it + 1) * BK);
            if (MUL) { const float4 rv = *(const float4*)(rptr + (it + 1) * BK);
                       av.x *= rv.x; av.y *= rv.y; av.z *= rv.z; av.w *= rv.w; }
            wv = *(const float4*)(wptr + (it + 1) * BK);
        }
        MAC_LOOP();
    }
    #pragma unroll
    for (int i = 0; i < 4; ++i) {
        const int m = bm + (ty << 2) + i;
        #pragma unroll
        for (int j = 0; j < 4; ++j)
            p[m * 512 + bn + (tx << 2) + j] = acc[i][j];
    }
}

// All input-only GEMM parts in one launch. z 0..5: d splits (K=1536) ->
// dbase slices 0..5 (hc1 dead space); z 6..13: r (0..3) / z (4..7) -> rzbase.
__global__ __launch_bounds__(256) void k_gemm_drz(
    const float* __restrict__ sample, const float* __restrict__ hidden,
    const float* __restrict__ d0,
    const float* __restrict__ Wd, const float* __restrict__ Wr,
    const float* __restrict__ Wz,
    float* __restrict__ dbase, float* __restrict__ rzbase)
{
    __shared__ float As[BK][BM + 4];
    __shared__ float Ws[BK][BN + 4];
    const int z = blockIdx.z;
    if (z < 6) {
        const int ks = z << 8, seg = ks >> 9;
        const float* ab = (seg == 0 ? sample : (seg == 1 ? hidden : d0)) + (ks & 511);
        gemm64<false>(As, Ws, ab, nullptr, Wd, 1536, ks,
                      blockIdx.y * BM, blockIdx.x * BN, 16, dbase + (size_t)z * BH);
    } else {
        const int id = z - 6, gz = id >> 2, s = id & 3, ks = s << 8;
        const float* ab = (ks < 512 ? sample + ks : hidden + (ks - 512));
        gemm64<false>(As, Ws, ab, nullptr, gz ? Wz : Wr, 1024, ks,
                      blockIdx.y * BM, blockIdx.x * BN, 16, rzbase + (size_t)id * BH);
    }
}

// dv/rb/zb reduce: consumes d-parts (hc1 slices 0..5, dead afterwards) and
// r/z parts (ws 0..7, dead afterwards -> reused for h-parts and accs).
__global__ __launch_bounds__(256) void k_dv(
    const float4* __restrict__ dparts, const float4* __restrict__ bd,
    const float4* __restrict__ rzparts, const float4* __restrict__ br,
    const float4* __restrict__ bz,
    float4* __restrict__ dv4, float4* __restrict__ rb4, float4* __restrict__ zb4)
{
    const int g = blockIdx.x * 256 + threadIdx.x;
    const int n = g & (H4 - 1);
    float4 sd = bd[n], sr = br[n], sz = bz[n];
    #pragma unroll
    for (int s = 0; s < 6; ++s) { const float4 p = dparts[(size_t)s * BH4 + g];
        sd.x += p.x; sd.y += p.y; sd.z += p.z; sd.w += p.w; }
    #pragma unroll
    for (int s = 0; s < 4; ++s) { const float4 p = rzparts[(size_t)s * BH4 + g];
        sr.x += p.x; sr.y += p.y; sr.z += p.z; sr.w += p.w; }
    #pragma unroll
    for (int s = 4; s < 8; ++s) { const float4 p = rzparts[(size_t)s * BH4 + g];
        sz.x += p.x; sz.y += p.y; sz.z += p.z; sz.w += p.w; }
    const float4 d = sig4(sd);
    dv4[g] = make_float4(0.5f * d.x, 0.5f * d.y, 0.5f * d.z, 0.5f * d.w);
    rb4[g] = sig4(sr);
    zb4[g] = sig4(sz);
}

// h-GEMM (r-gate applied on the fly): parts -> ws slices 0..3
__global__ __launch_bounds__(256) void k_gemm_h(
    const float* __restrict__ sample, const float* __restrict__ hidden,
    const float* __restrict__ rb, const float* __restrict__ Wh,
    float* __restrict__ parts)
{
    __shared__ float As[BK][BM + 4];
    __shared__ float Ws[BK][BN + 4];
    const int s = blockIdx.z, ks = s << 8;
    if (ks < 512)
        gemm64<false>(As, Ws, sample + ks, nullptr, Wh, 1024, ks,
                      blockIdx.y * BM, blockIdx.x * BN, 16, parts + (size_t)s * BH);
    else
        gemm64<true>(As, Ws, hidden + (ks - 512), rb + (ks - 512), Wh, 1024, ks,
                     blockIdx.y * BM, blockIdx.x * BN, 16, parts + (size_t)s * BH);
}

// ---------------------------------------------------------------------------
// Pure filter: float4 columns (16 B/lane loads AND stores — m13 copy shape),
// 4 K-segments. Segment s: t = 64s..64s+63, k = 255-t, local cumprod from 1.
// acc_s -> ws slices 4..7. hc1 slice writes disjoint across segments.
// ---------------------------------------------------------------------------
__global__ __launch_bounds__(256, 4) void k_filter(
    const float4* __restrict__ ht4, const float4* __restrict__ dv4,
    float4* __restrict__ acc_out, float4* __restrict__ hc14)
{
    __shared__ float s_inv[KF], s_tinv[KF];
    const int tid = threadIdx.x;
    const float fi = 1.0f / (float)(tid + 1);
    s_inv[tid] = fi; s_tinv[tid] = (float)tid * fi;
    __syncthreads();

    const int seg = blockIdx.x >> 7;                 // 0..3
    const int q   = ((blockIdx.x & 127) << 8) | tid; // float4-column 0..32767
    const float4 d = dv4[q];
    const int t0 = seg << 6;

    float4 c = make_float4(1.f, 1.f, 1.f, 1.f);
    float4 a = make_float4(0.f, 0.f, 0.f, 0.f);
    #pragma unroll 8
    for (int i = 0; i < 64; ++i) {
        const int t = t0 + i;
        const int k = 255 - t;
        const float4 v = ht4[(size_t)k * BH4 + q];
        const float iv = s_inv[t], tv = s_tinv[t];
        c.x *= fmaf(-d.x, iv, tv);                   // (t - d)/(t + 1)
        c.y *= fmaf(-d.y, iv, tv);
        c.z *= fmaf(-d.z, iv, tv);
        c.w *= fmaf(-d.w, iv, tv);
        a.x = fmaf(v.x, c.x, a.x);
        a.y = fmaf(v.y, c.y, a.y);
        a.z = fmaf(v.z, c.z, a.z);
        a.w = fmaf(v.w, c.w, a.w);
        if (k >= 1) hc14[(size_t)(k - 1) * BH4 + q] = v;   // uniform branch
    }
    acc_out[(size_t)seg * BH4 + q] = a;
}

// finalize: recompute segment-prefix products from dv (192-step chain),
// combine 4 segment accs, h-parts reduce, hn = tanh(.)*(1-z) - acc.
__global__ __launch_bounds__(256) void k_finalize(
    const float4* __restrict__ dv4, const float4* __restrict__ ws4,
    const float4* __restrict__ bh, const float4* __restrict__ zb4,
    float4* hc1_4, float4* __restrict__ hn_out)
{
    __shared__ float s_inv[192], s_tinv[192];
    const int tid = threadIdx.x;
    if (tid < 192) { const float fi = 1.0f / (float)(tid + 1);
                     s_inv[tid] = fi; s_tinv[tid] = (float)tid * fi; }
    __syncthreads();

    const int g = blockIdx.x * 256 + tid;
    const int n = g & (H4 - 1);
    const float4 d = dv4[g];

    float4 c = make_float4(1.f, 1.f, 1.f, 1.f), px0, px1, px2;
    #pragma unroll 16
    for (int t = 0; t < 64; ++t) {
        const float iv = s_inv[t], tv = s_tinv[t];
        c.x *= fmaf(-d.x, iv, tv); c.y *= fmaf(-d.y, iv, tv);
        c.z *= fmaf(-d.z, iv, tv); c.w *= fmaf(-d.w, iv, tv);
    }
    px0 = c;
    #pragma unroll 16
    for (int t = 64; t < 128; ++t) {
        const float iv = s_inv[t], tv = s_tinv[t];
        c.x *= fmaf(-d.x, iv, tv); c.y *= fmaf(-d.y, iv, tv);
        c.z *= fmaf(-d.z, iv, tv); c.w *= fmaf(-d.w, iv, tv);
    }
    px1 = c;
    #pragma unroll 16
    for (int t = 128; t < 192; ++t) {
        const float iv = s_inv[t], tv = s_tinv[t];
        c.x *= fmaf(-d.x, iv, tv); c.y *= fmaf(-d.y, iv, tv);
        c.z *= fmaf(-d.z, iv, tv); c.w *= fmaf(-d.w, iv, tv);
    }
    px2 = c;

    const float4 a0 = ws4[(size_t)4 * BH4 + g];
    const float4 a1 = ws4[(size_t)5 * BH4 + g];
    const float4 a2 = ws4[(size_t)6 * BH4 + g];
    const float4 a3 = ws4[(size_t)7 * BH4 + g];
    float4 hs = bh[n];
    #pragma unroll
    for (int s = 0; s < 4; ++s) { const float4 p = ws4[(size_t)s * BH4 + g];
        hs.x += p.x; hs.y += p.y; hs.z += p.z; hs.w += p.w; }
    const float4 z = zb4[g];

    float4 hn;
    hn.x = tanh_fast(hs.x) * (1.0f - z.x)
         - (a0.x + px0.x * a1.x + px1.x * a2.x + px2.x * a3.x);
    hn.y = tanh_fast(hs.y) * (1.0f - z.y)
         - (a0.y + px0.y * a1.y + px1.y * a2.y + px2.y * a3.y);
    hn.z = tanh_fast(hs.z) * (1.0f - z.z)
         - (a0.z + px0.z * a1.z + px1.z * a2.z + px2.z * a3.z);
    hn.w = tanh_fast(hs.w) * (1.0f - z.w)
         - (a0.w + px0.w * a1.w + px1.w * a2.w + px2.w * a3.w);
    hn_out[g] = hn;
    hc1_4[(size_t)255 * BH4 + g] = hn;
}

__global__ __launch_bounds__(256) void k_gemm_o(
    const float* __restrict__ hn, const float* __restrict__ Wo,
    float* __restrict__ parts, int chunk)
{
    __shared__ float As[BK][BM + 4];
    __shared__ float Ws[BK][BN + 4];
    const int s = blockIdx.z, ks = s * chunk;
    gemm64<false>(As, Ws, hn + ks, nullptr, Wo, 512, ks,
                  blockIdx.y * BM, blockIdx.x * BN, chunk / BK, parts + (size_t)s * BH);
}

// no __restrict__: fallback path calls with parts == out (same-thread RMW)
__global__ __launch_bounds__(256) void k_reduce_o(
    const float4* parts, const float4* __restrict__ bo, float4* out, int NS)
{
    const int g = blockIdx.x * 256 + threadIdx.x;
    float4 v = bo[g & (H4 - 1)];
    for (int s = 0; s < NS; ++s) { const float4 p = parts[(size_t)s * BH4 + g];
        v.x += p.x; v.y += p.y; v.z += p.z; v.w += p.w; }
    out[g] = v;
}

// ------------------------- fallback-only kernels ---------------------------
__global__ __launch_bounds__(256) void k_reduce_rz(
    const float4* __restrict__ parts, const float4* __restrict__ br,
    const float4* __restrict__ bz, float4* __restrict__ rb, float4* __restrict__ zb)
{
    const int g = blockIdx.x * 256 + threadIdx.x;
    const int n = g & (H4 - 1);
    float4 r = br[n], z = bz[n];
    #pragma unroll
    for (int s = 0; s < 4; ++s) { const float4 p = parts[(size_t)s * BH4 + g];
        r.x += p.x; r.y += p.y; r.z += p.z; r.w += p.w; }
    #pragma unroll
    for (int s = 4; s < 8; ++s) { const float4 p = parts[(size_t)s * BH4 + g];
        z.x += p.x; z.y += p.y; z.z += p.z; z.w += p.w; }
    rb[g] = sig4(r); zb[g] = sig4(z);
}

__global__ __launch_bounds__(256) void k_filter_full(
    const float* __restrict__ ht, const float* dparts, const float* __restrict__ bd,
    const float* zbuf, const float* hparts, const float* __restrict__ bh,
    float* hc1, float* __restrict__ dv_out, float* __restrict__ hn_out)
{
    __shared__ float s_inv[KF], s_tinv[KF];
    const int tid = threadIdx.x;
    const float fi = 1.0f / (float)(tid + 1);
    s_inv[tid] = fi; s_tinv[tid] = (float)tid * fi;
    __syncthreads();

    const int g = blockIdx.x * 256 + tid;
    const int n = g & (H_ - 1);
    float sd = bd[n];
    #pragma unroll
    for (int s = 0; s < 6; ++s) sd += dparts[(size_t)s * BH + g];
    const float d = 0.5f * sigmoidf_(sd);
    dv_out[g] = d;
    float sh = bh[n];
    #pragma unroll
    for (int s = 0; s < 4; ++s) sh += hparts[(size_t)s * BH + g];
    const float z = zbuf[g];

    float c = 1.0f, acc = 0.0f;
    #pragma unroll 16
    for (int t = 0; t < KF; ++t) {
        const int k = KF - 1 - t;
        const float v = ht[(size_t)k * BH + g];
        c *= fmaf(-d, s_inv[t], s_tinv[t]);
        acc = fmaf(v, c, acc);
        if (k >= 1) hc1[(size_t)(k - 1) * BH + g] = v;
    }
    const float hn = tanh_fast(sh) * (1.0f - z) - acc;
    hc1[(size_t)(KF - 1) * BH + g] = hn;
    hn_out[g] = hn;
}

extern "C" void kernel_launch(void* const* d_in, const int* in_sizes, int n_in,
                              void* d_out, int out_size, void* d_ws, size_t ws_size,
                              hipStream_t stream)
{
    const float* sample = (const float*)d_in[0];
    const float* hidden = (const float*)d_in[1];
    const float* ht     = (const float*)d_in[2];
    const float* d0     = (const float*)d_in[3];
    const float* Wd = (const float*)d_in[4];
    const float* bd = (const float*)d_in[5];
    const float* Wr = (const float*)d_in[6];
    const float* br = (const float*)d_in[7];
    const float* Wz = (const float*)d_in[8];
    const float* bz = (const float*)d_in[9];
    const float* Wh = (const float*)d_in[10];
    const float* bh = (const float*)d_in[11];
    const float* Wo = (const float*)d_in[12];
    const float* bo = (const float*)d_in[13];

    float* out     = (float*)d_out;
    float* out_o   = out;
    float* out_hn  = out + BH;
    float* out_hc1 = out + 2 * BH;
    float* out_dv  = out + 2 * BH + (size_t)KF * BH;

    const size_t slice = BH;
    const size_t need = 10ull * slice * sizeof(float);

    if (ws_size >= need) {
        float* ws = (float*)d_ws;
        // ws: [0..3] r-parts -> h-parts (after k_dv) -> o-parts (after finalize)
        //     [4..7] z-parts -> filter segment accs (after k_dv)
        //     [8] rb, [9] zb.  d-parts -> hc1 slices 0..5 (dead after k_dv).
        float* rb = ws + 8 * slice;
        float* zb = ws + 9 * slice;

        k_gemm_drz<<<dim3(8, 4, 14), 256, 0, stream>>>(sample, hidden, d0,
                                                       Wd, Wr, Wz, out_hc1, ws);
        k_dv<<<dim3(128), 256, 0, stream>>>(
            (const float4*)out_hc1, (const float4*)bd,
            (const float4*)ws, (const float4*)br, (const float4*)bz,
            (float4*)out_dv, (float4*)rb, (float4*)zb);
        k_gemm_h<<<dim3(8, 4, 4), 256, 0, stream>>>(sample, hidden, rb, Wh, ws);
        k_filter<<<dim3(512), 256, 0, stream>>>(
            (const float4*)ht, (const float4*)out_dv,
            (float4*)(ws + 4 * slice), (float4*)out_hc1);
        k_finalize<<<dim3(128), 256, 0, stream>>>(
            (const float4*)out_dv, (const float4*)ws,
            (const float4*)bh, (const float4*)zb,
            (float4*)out_hc1, (float4*)out_hn);
        k_gemm_o<<<dim3(8, 4, 4), 256, 0, stream>>>(out_hn, Wo, ws, 128);
        k_reduce_o<<<dim3(128), 256, 0, stream>>>((const float4*)ws,
                                                  (const float4*)bo,
                                                  (float4*)out_o, 4);
    } else {
        // serial fallback, all scratch = dead hc1 slices
        float* sl = out_hc1;
        k_gemm_drz<<<dim3(8, 4, 14), 256, 0, stream>>>(sample, hidden, d0,
                                                       Wd, Wr, Wz, sl, sl + 6 * slice);
        k_reduce_rz<<<dim3(128), 256, 0, stream>>>((const float4*)(sl + 6 * slice),
                                                   (const float4*)br, (const float4*)bz,
                                                   (float4*)(sl + 14 * slice),
                                                   (float4*)(sl + 15 * slice));
        k_gemm_h<<<dim3(8, 4, 4), 256, 0, stream>>>(sample, hidden, sl + 14 * slice, Wh,
                                                    sl + 16 * slice);
        k_filter_full<<<dim3(512), 256, 0, stream>>>(ht, sl, bd, sl + 15 * slice,
                                                     sl + 16 * slice, bh,
                                                     out_hc1, out_dv, out_hn);
        k_gemm_o<<<dim3(8, 4, 1), 256, 0, stream>>>(out_hn, Wo, out_o, 512);
        k_reduce_o<<<dim3(128), 256, 0, stream>>>((const float4*)out_o, (const float4*)bo,
                                                  (float4*)out_o, 1);
    }
}

// Round 7
// 101.836 us; speedup vs baseline: 1.1261x; 1.1261x over previous
//
#include <hip/hip_runtime.h>
#include <cstddef>

#define B_ 256
#define H_ 512
#define KF 256
#define BH 131072    // B_*H_
#define BH2 65536    // BH/2
#define BH4 32768    // BH/4
#define H4 128       // H_/4

#define BM 64
#define BN 64
#define BK 16

__device__ __forceinline__ float sigmoidf_(float x) { return 1.0f / (1.0f + __expf(-x)); }
__device__ __forceinline__ float tanh_fast(float x) { return 2.0f / (1.0f + __expf(-2.0f * x)) - 1.0f; }
__device__ __forceinline__ float4 sig4(float4 v) {
    return make_float4(sigmoidf_(v.x), sigmoidf_(v.y), sigmoidf_(v.z), sigmoidf_(v.w));
}

#define MAC_LOOP()                                                         \
    _Pragma("unroll")                                                      \
    for (int kk = 0; kk < BK; ++kk) {                                      \
        const float4 a = *(const float4*)&As[kk][ty << 2];                 \
        const float4 w = *(const float4*)&Ws[kk][tx << 2];                 \
        const float a4[4] = {a.x, a.y, a.z, a.w};                          \
        const float w4[4] = {w.x, w.y, w.z, w.w};                          \
        _Pragma("unroll")                                                  \
        for (int i = 0; i < 4; ++i)                                        \
            _Pragma("unroll")                                              \
            for (int j = 0; j < 4; ++j)                                    \
                acc[i][j] = fmaf(a4[i], w4[j], acc[i][j]);                 \
    }

// ---------------------------------------------------------------------------
// 64x64-tile split-K partial GEMM over a K-chunk, register double-stage.
// ---------------------------------------------------------------------------
template<bool MUL>
__device__ __forceinline__ void gemm64(
    float (*As)[BM + 4], float (*Ws)[BN + 4],
    const float* __restrict__ abase, const float* __restrict__ rbase,
    const float* __restrict__ W, int Ktot, int ks,
    int bm, int bn, int nIter, float* __restrict__ p)
{
    const int tid = threadIdx.x;
    const int ty = tid >> 4, tx = tid & 15;
    const int lrow = tid >> 2, lcol = (tid & 3) << 2;
    const float* aptr = abase + (bm + lrow) * 512 + lcol;
    const float* rptr = MUL ? rbase + (bm + lrow) * 512 + lcol : nullptr;
    const float* wptr = W + (size_t)(bn + lrow) * Ktot + ks + lcol;

    float acc[4][4] = {};
    float4 av = *(const float4*)aptr;
    if (MUL) { const float4 rv = *(const float4*)rptr;
               av.x *= rv.x; av.y *= rv.y; av.z *= rv.z; av.w *= rv.w; }
    float4 wv = *(const float4*)wptr;

    for (int it = 0; it < nIter; ++it) {
        __syncthreads();
        As[lcol + 0][lrow] = av.x; As[lcol + 1][lrow] = av.y;
        As[lcol + 2][lrow] = av.z; As[lcol + 3][lrow] = av.w;
        Ws[lcol + 0][lrow] = wv.x; Ws[lcol + 1][lrow] = wv.y;
        Ws[lcol + 2][lrow] = wv.z; Ws[lcol + 3][lrow] = wv.w;
        __syncthreads();
        if (it < nIter - 1) {
            av = *(const float4*)(aptr + (it + 1) * BK);
            if (MUL) { const float4 rv = *(const float4*)(rptr + (it + 1) * BK);
                       av.x *= rv.x; av.y *= rv.y; av.z *= rv.z; av.w *= rv.w; }
            wv = *(const float4*)(wptr + (it + 1) * BK);
        }
        MAC_LOOP();
    }
    #pragma unroll
    for (int i = 0; i < 4; ++i) {
        const int m = bm + (ty << 2) + i;
        #pragma unroll
        for (int j = 0; j < 4; ++j)
            p[m * 512 + bn + (tx << 2) + j] = acc[i][j];
    }
}

// All input-only GEMM parts in one launch. z 0..5: d splits (K=1536) ->
// dbase slices 0..5 (hc1 dead space); z 6..13: r (0..3) / z (4..7) -> rzbase.
__global__ __launch_bounds__(256) void k_gemm_drz(
    const float* __restrict__ sample, const float* __restrict__ hidden,
    const float* __restrict__ d0,
    const float* __restrict__ Wd, const float* __restrict__ Wr,
    const float* __restrict__ Wz,
    float* __restrict__ dbase, float* __restrict__ rzbase)
{
    __shared__ float As[BK][BM + 4];
    __shared__ float Ws[BK][BN + 4];
    const int z = blockIdx.z;
    if (z < 6) {
        const int ks = z << 8, seg = ks >> 9;
        const float* ab = (seg == 0 ? sample : (seg == 1 ? hidden : d0)) + (ks & 511);
        gemm64<false>(As, Ws, ab, nullptr, Wd, 1536, ks,
                      blockIdx.y * BM, blockIdx.x * BN, 16, dbase + (size_t)z * BH);
    } else {
        const int id = z - 6, gz = id >> 2, s = id & 3, ks = s << 8;
        const float* ab = (ks < 512 ? sample + ks : hidden + (ks - 512));
        gemm64<false>(As, Ws, ab, nullptr, gz ? Wz : Wr, 1024, ks,
                      blockIdx.y * BM, blockIdx.x * BN, 16, rzbase + (size_t)id * BH);
    }
}

// dv/rb/zb reduce: consumes d-parts (hc1 slices 0..5, dead afterwards) and
// r/z parts (ws 0..7, dead afterwards -> reused for h-parts and accs).
__global__ __launch_bounds__(256) void k_dv(
    const float4* __restrict__ dparts, const float4* __restrict__ bd,
    const float4* __restrict__ rzparts, const float4* __restrict__ br,
    const float4* __restrict__ bz,
    float4* __restrict__ dv4, float4* __restrict__ rb4, float4* __restrict__ zb4)
{
    const int g = blockIdx.x * 256 + threadIdx.x;
    const int n = g & (H4 - 1);
    float4 sd = bd[n], sr = br[n], sz = bz[n];
    #pragma unroll
    for (int s = 0; s < 6; ++s) { const float4 p = dparts[(size_t)s * BH4 + g];
        sd.x += p.x; sd.y += p.y; sd.z += p.z; sd.w += p.w; }
    #pragma unroll
    for (int s = 0; s < 4; ++s) { const float4 p = rzparts[(size_t)s * BH4 + g];
        sr.x += p.x; sr.y += p.y; sr.z += p.z; sr.w += p.w; }
    #pragma unroll
    for (int s = 4; s < 8; ++s) { const float4 p = rzparts[(size_t)s * BH4 + g];
        sz.x += p.x; sz.y += p.y; sz.z += p.z; sz.w += p.w; }
    const float4 d = sig4(sd);
    dv4[g] = make_float4(0.5f * d.x, 0.5f * d.y, 0.5f * d.z, 0.5f * d.w);
    rb4[g] = sig4(sr);
    zb4[g] = sig4(sz);
}

// h-GEMM (r-gate applied on the fly): parts -> ws slices 0..3
__global__ __launch_bounds__(256) void k_gemm_h(
    const float* __restrict__ sample, const float* __restrict__ hidden,
    const float* __restrict__ rb, const float* __restrict__ Wh,
    float* __restrict__ parts)
{
    __shared__ float As[BK][BM + 4];
    __shared__ float Ws[BK][BN + 4];
    const int s = blockIdx.z, ks = s << 8;
    if (ks < 512)
        gemm64<false>(As, Ws, sample + ks, nullptr, Wh, 1024, ks,
                      blockIdx.y * BM, blockIdx.x * BN, 16, parts + (size_t)s * BH);
    else
        gemm64<true>(As, Ws, hidden + (ks - 512), rb + (ks - 512), Wh, 1024, ks,
                     blockIdx.y * BM, blockIdx.x * BN, 16, parts + (size_t)s * BH);
}

// ---------------------------------------------------------------------------
// Filter, batch-8 double-buffered: 8 independent float4 loads in flight,
// branch-free body. The k=0 store lands one slice BELOW hc1 (= out_hn region,
// fully overwritten by k_finalize afterwards) -> unconditional store.
// 4 K-segments x 128 blocks. Segment s: t = 64s..64s+63, k = 255-t.
// ---------------------------------------------------------------------------
#define FLOADB(buf, b)                                                     \
    _Pragma("unroll")                                                      \
    for (int u = 0; u < 8; ++u)                                            \
        buf[u] = ld_base[-(ptrdiff_t)((b) * 8 + u) * BH4];

#define FCSTORE(buf, b)                                                    \
    _Pragma("unroll")                                                      \
    for (int u = 0; u < 8; ++u) {                                          \
        const int t = t0 + (b) * 8 + u;                                    \
        const float iv = s_inv[t], tv = s_tinv[t];                         \
        c.x *= fmaf(-d.x, iv, tv); c.y *= fmaf(-d.y, iv, tv);              \
        c.z *= fmaf(-d.z, iv, tv); c.w *= fmaf(-d.w, iv, tv);              \
        a.x = fmaf(buf[u].x, c.x, a.x); a.y = fmaf(buf[u].y, c.y, a.y);    \
        a.z = fmaf(buf[u].z, c.z, a.z); a.w = fmaf(buf[u].w, c.w, a.w);    \
        st_base[-(ptrdiff_t)((b) * 8 + u) * BH4] = buf[u];                 \
    }

__global__ __launch_bounds__(256) void k_filter(
    const float4* __restrict__ ht4, const float4* __restrict__ dv4,
    float4* __restrict__ acc_out, float4* __restrict__ hc14)
{
    __shared__ float s_inv[KF], s_tinv[KF];
    const int tid = threadIdx.x;
    const float fi = 1.0f / (float)(tid + 1);
    s_inv[tid] = fi; s_tinv[tid] = (float)tid * fi;
    __syncthreads();

    const int seg = blockIdx.x >> 7;                 // 0..3
    const int q   = ((blockIdx.x & 127) << 8) | tid; // float4-column 0..32767
    const float4 d = dv4[q];
    const int t0 = seg << 6;

    const float4* ld_base = ht4 + (size_t)(255 - t0) * BH4 + q;
    float4*       st_base = hc14 + (ptrdiff_t)(254 - t0) * BH4 + q;

    float4 c = make_float4(1.f, 1.f, 1.f, 1.f);
    float4 a = make_float4(0.f, 0.f, 0.f, 0.f);

    float4 va[8], vb[8];
    FLOADB(va, 0);
    #pragma unroll
    for (int b = 0; b < 8; b += 2) {
        FLOADB(vb, b + 1);
        FCSTORE(va, b);
        if (b + 2 < 8) { FLOADB(va, b + 2); }
        FCSTORE(vb, b + 1);
    }
    acc_out[(size_t)seg * BH4 + q] = a;
}

// finalize: recompute segment-prefix products from dv (192-step chain),
// combine 4 segment accs, h-parts reduce, hn = tanh(.)*(1-z) - acc.
__global__ __launch_bounds__(256) void k_finalize(
    const float4* __restrict__ dv4, const float4* __restrict__ ws4,
    const float4* __restrict__ bh, const float4* __restrict__ zb4,
    float4* hc1_4, float4* __restrict__ hn_out)
{
    __shared__ float s_inv[192], s_tinv[192];
    const int tid = threadIdx.x;
    if (tid < 192) { const float fi = 1.0f / (float)(tid + 1);
                     s_inv[tid] = fi; s_tinv[tid] = (float)tid * fi; }
    __syncthreads();

    const int g = blockIdx.x * 256 + tid;
    const int n = g & (H4 - 1);
    const float4 d = dv4[g];

    float4 c = make_float4(1.f, 1.f, 1.f, 1.f), px0, px1, px2;
    #pragma unroll 16
    for (int t = 0; t < 64; ++t) {
        const float iv = s_inv[t], tv = s_tinv[t];
        c.x *= fmaf(-d.x, iv, tv); c.y *= fmaf(-d.y, iv, tv);
        c.z *= fmaf(-d.z, iv, tv); c.w *= fmaf(-d.w, iv, tv);
    }
    px0 = c;
    #pragma unroll 16
    for (int t = 64; t < 128; ++t) {
        const float iv = s_inv[t], tv = s_tinv[t];
        c.x *= fmaf(-d.x, iv, tv); c.y *= fmaf(-d.y, iv, tv);
        c.z *= fmaf(-d.z, iv, tv); c.w *= fmaf(-d.w, iv, tv);
    }
    px1 = c;
    #pragma unroll 16
    for (int t = 128; t < 192; ++t) {
        const float iv = s_inv[t], tv = s_tinv[t];
        c.x *= fmaf(-d.x, iv, tv); c.y *= fmaf(-d.y, iv, tv);
        c.z *= fmaf(-d.z, iv, tv); c.w *= fmaf(-d.w, iv, tv);
    }
    px2 = c;

    const float4 a0 = ws4[(size_t)4 * BH4 + g];
    const float4 a1 = ws4[(size_t)5 * BH4 + g];
    const float4 a2 = ws4[(size_t)6 * BH4 + g];
    const float4 a3 = ws4[(size_t)7 * BH4 + g];
    float4 hs = bh[n];
    #pragma unroll
    for (int s = 0; s < 4; ++s) { const float4 p = ws4[(size_t)s * BH4 + g];
        hs.x += p.x; hs.y += p.y; hs.z += p.z; hs.w += p.w; }
    const float4 z = zb4[g];

    float4 hn;
    hn.x = tanh_fast(hs.x) * (1.0f - z.x)
         - (a0.x + px0.x * a1.x + px1.x * a2.x + px2.x * a3.x);
    hn.y = tanh_fast(hs.y) * (1.0f - z.y)
         - (a0.y + px0.y * a1.y + px1.y * a2.y + px2.y * a3.y);
    hn.z = tanh_fast(hs.z) * (1.0f - z.z)
         - (a0.z + px0.z * a1.z + px1.z * a2.z + px2.z * a3.z);
    hn.w = tanh_fast(hs.w) * (1.0f - z.w)
         - (a0.w + px0.w * a1.w + px1.w * a2.w + px2.w * a3.w);
    hn_out[g] = hn;
    hc1_4[(size_t)255 * BH4 + g] = hn;
}

__global__ __launch_bounds__(256) void k_gemm_o(
    const float* __restrict__ hn, const float* __restrict__ Wo,
    float* __restrict__ parts, int chunk)
{
    __shared__ float As[BK][BM + 4];
    __shared__ float Ws[BK][BN + 4];
    const int s = blockIdx.z, ks = s * chunk;
    gemm64<false>(As, Ws, hn + ks, nullptr, Wo, 512, ks,
                  blockIdx.y * BM, blockIdx.x * BN, chunk / BK, parts + (size_t)s * BH);
}

// no __restrict__: fallback path calls with parts == out (same-thread RMW)
__global__ __launch_bounds__(256) void k_reduce_o(
    const float4* parts, const float4* __restrict__ bo, float4* out, int NS)
{
    const int g = blockIdx.x * 256 + threadIdx.x;
    float4 v = bo[g & (H4 - 1)];
    for (int s = 0; s < NS; ++s) { const float4 p = parts[(size_t)s * BH4 + g];
        v.x += p.x; v.y += p.y; v.z += p.z; v.w += p.w; }
    out[g] = v;
}

// ------------------------- fallback-only kernels ---------------------------
__global__ __launch_bounds__(256) void k_reduce_rz(
    const float4* __restrict__ parts, const float4* __restrict__ br,
    const float4* __restrict__ bz, float4* __restrict__ rb, float4* __restrict__ zb)
{
    const int g = blockIdx.x * 256 + threadIdx.x;
    const int n = g & (H4 - 1);
    float4 r = br[n], z = bz[n];
    #pragma unroll
    for (int s = 0; s < 4; ++s) { const float4 p = parts[(size_t)s * BH4 + g];
        r.x += p.x; r.y += p.y; r.z += p.z; r.w += p.w; }
    #pragma unroll
    for (int s = 4; s < 8; ++s) { const float4 p = parts[(size_t)s * BH4 + g];
        z.x += p.x; z.y += p.y; z.z += p.z; z.w += p.w; }
    rb[g] = sig4(r); zb[g] = sig4(z);
}

__global__ __launch_bounds__(256) void k_filter_full(
    const float* __restrict__ ht, const float* dparts, const float* __restrict__ bd,
    const float* zbuf, const float* hparts, const float* __restrict__ bh,
    float* hc1, float* __restrict__ dv_out, float* __restrict__ hn_out)
{
    __shared__ float s_inv[KF], s_tinv[KF];
    const int tid = threadIdx.x;
    const float fi = 1.0f / (float)(tid + 1);
    s_inv[tid] = fi; s_tinv[tid] = (float)tid * fi;
    __syncthreads();

    const int g = blockIdx.x * 256 + tid;
    const int n = g & (H_ - 1);
    float sd = bd[n];
    #pragma unroll
    for (int s = 0; s < 6; ++s) sd += dparts[(size_t)s * BH + g];
    const float d = 0.5f * sigmoidf_(sd);
    dv_out[g] = d;
    float sh = bh[n];
    #pragma unroll
    for (int s = 0; s < 4; ++s) sh += hparts[(size_t)s * BH + g];
    const float z = zbuf[g];

    float c = 1.0f, acc = 0.0f;
    #pragma unroll 16
    for (int t = 0; t < KF; ++t) {
        const int k = KF - 1 - t;
        const float v = ht[(size_t)k * BH + g];
        c *= fmaf(-d, s_inv[t], s_tinv[t]);
        acc = fmaf(v, c, acc);
        if (k >= 1) hc1[(size_t)(k - 1) * BH + g] = v;
    }
    const float hn = tanh_fast(sh) * (1.0f - z) - acc;
    hc1[(size_t)(KF - 1) * BH + g] = hn;
    hn_out[g] = hn;
}

extern "C" void kernel_launch(void* const* d_in, const int* in_sizes, int n_in,
                              void* d_out, int out_size, void* d_ws, size_t ws_size,
                              hipStream_t stream)
{
    const float* sample = (const float*)d_in[0];
    const float* hidden = (const float*)d_in[1];
    const float* ht     = (const float*)d_in[2];
    const float* d0     = (const float*)d_in[3];
    const float* Wd = (const float*)d_in[4];
    const float* bd = (const float*)d_in[5];
    const float* Wr = (const float*)d_in[6];
    const float* br = (const float*)d_in[7];
    const float* Wz = (const float*)d_in[8];
    const float* bz = (const float*)d_in[9];
    const float* Wh = (const float*)d_in[10];
    const float* bh = (const float*)d_in[11];
    const float* Wo = (const float*)d_in[12];
    const float* bo = (const float*)d_in[13];

    float* out     = (float*)d_out;
    float* out_o   = out;
    float* out_hn  = out + BH;
    float* out_hc1 = out + 2 * BH;
    float* out_dv  = out + 2 * BH + (size_t)KF * BH;

    const size_t slice = BH;
    const size_t need = 10ull * slice * sizeof(float);

    if (ws_size >= need) {
        float* ws = (float*)d_ws;
        // ws: [0..3] r-parts -> h-parts (after k_dv) -> o-parts (after finalize)
        //     [4..7] z-parts -> filter segment accs (after k_dv)
        //     [8] rb, [9] zb.  d-parts -> hc1 slices 0..5 (dead after k_dv).
        float* rb = ws + 8 * slice;
        float* zb = ws + 9 * slice;

        k_gemm_drz<<<dim3(8, 4, 14), 256, 0, stream>>>(sample, hidden, d0,
                                                       Wd, Wr, Wz, out_hc1, ws);
        k_dv<<<dim3(128), 256, 0, stream>>>(
            (const float4*)out_hc1, (const float4*)bd,
            (const float4*)ws, (const float4*)br, (const float4*)bz,
            (float4*)out_dv, (float4*)rb, (float4*)zb);
        k_gemm_h<<<dim3(8, 4, 4), 256, 0, stream>>>(sample, hidden, rb, Wh, ws);
        k_filter<<<dim3(512), 256, 0, stream>>>(
            (const float4*)ht, (const float4*)out_dv,
            (float4*)(ws + 4 * slice), (float4*)out_hc1);
        k_finalize<<<dim3(128), 256, 0, stream>>>(
            (const float4*)out_dv, (const float4*)ws,
            (const float4*)bh, (const float4*)zb,
            (float4*)out_hc1, (float4*)out_hn);
        k_gemm_o<<<dim3(8, 4, 4), 256, 0, stream>>>(out_hn, Wo, ws, 128);
        k_reduce_o<<<dim3(128), 256, 0, stream>>>((const float4*)ws,
                                                  (const float4*)bo,
                                                  (float4*)out_o, 4);
    } else {
        // serial fallback, all scratch = dead hc1 slices
        float* sl = out_hc1;
        k_gemm_drz<<<dim3(8, 4, 14), 256, 0, stream>>>(sample, hidden, d0,
                                                       Wd, Wr, Wz, sl, sl + 6 * slice);
        k_reduce_rz<<<dim3(128), 256, 0, stream>>>((const float4*)(sl + 6 * slice),
                                                   (const float4*)br, (const float4*)bz,
                                                   (float4*)(sl + 14 * slice),
                                                   (float4*)(sl + 15 * slice));
        k_gemm_h<<<dim3(8, 4, 4), 256, 0, stream>>>(sample, hidden, sl + 14 * slice, Wh,
                                                    sl + 16 * slice);
        k_filter_full<<<dim3(512), 256, 0, stream>>>(ht, sl, bd, sl + 15 * slice,
                                                     sl + 16 * slice, bh,
                                                     out_hc1, out_dv, out_hn);
        k_gemm_o<<<dim3(8, 4, 1), 256, 0, stream>>>(out_hn, Wo, out_o, 512);
        k_reduce_o<<<dim3(128), 256, 0, stream>>>((const float4*)out_o, (const float4*)bo,
                                                  (float4*)out_o, 1);
    }
}

// Round 9
// 84.957 us; speedup vs baseline: 1.3498x; 1.1987x over previous
//
#include <hip/hip_runtime.h>
#include <cstddef>

#define B_ 256
#define H_ 512
#define KF 256
#define BH 131072    // B_*H_
#define BH2 65536    // BH/2
#define BH4 32768    // BH/4
#define H4 128       // H_/4

#define BM 64
#define BN 64
#define BK 16

typedef float nf4 __attribute__((ext_vector_type(4)));

__device__ __forceinline__ float sigmoidf_(float x) { return 1.0f / (1.0f + __expf(-x)); }
__device__ __forceinline__ float tanh_fast(float x) { return 2.0f / (1.0f + __expf(-2.0f * x)) - 1.0f; }
__device__ __forceinline__ float4 sig4(float4 v) {
    return make_float4(sigmoidf_(v.x), sigmoidf_(v.y), sigmoidf_(v.z), sigmoidf_(v.w));
}

#define MAC_LOOP()                                                         \
    _Pragma("unroll")                                                      \
    for (int kk = 0; kk < BK; ++kk) {                                      \
        const float4 a = *(const float4*)&As[kk][ty << 2];                 \
        const float4 w = *(const float4*)&Ws[kk][tx << 2];                 \
        const float a4[4] = {a.x, a.y, a.z, a.w};                          \
        const float w4[4] = {w.x, w.y, w.z, w.w};                          \
        _Pragma("unroll")                                                  \
        for (int i = 0; i < 4; ++i)                                        \
            _Pragma("unroll")                                              \
            for (int j = 0; j < 4; ++j)                                    \
                acc[i][j] = fmaf(a4[i], w4[j], acc[i][j]);                 \
    }

// ---------------------------------------------------------------------------
// 64x64-tile split-K partial GEMM over a K-chunk, register double-stage.
// ---------------------------------------------------------------------------
template<bool MUL>
__device__ __forceinline__ void gemm64(
    float (*As)[BM + 4], float (*Ws)[BN + 4],
    const float* __restrict__ abase, const float* __restrict__ rbase,
    const float* __restrict__ W, int Ktot, int ks,
    int bm, int bn, int nIter, float* __restrict__ p)
{
    const int tid = threadIdx.x;
    const int ty = tid >> 4, tx = tid & 15;
    const int lrow = tid >> 2, lcol = (tid & 3) << 2;
    const float* aptr = abase + (bm + lrow) * 512 + lcol;
    const float* rptr = MUL ? rbase + (bm + lrow) * 512 + lcol : nullptr;
    const float* wptr = W + (size_t)(bn + lrow) * Ktot + ks + lcol;

    float acc[4][4] = {};
    float4 av = *(const float4*)aptr;
    if (MUL) { const float4 rv = *(const float4*)rptr;
               av.x *= rv.x; av.y *= rv.y; av.z *= rv.z; av.w *= rv.w; }
    float4 wv = *(const float4*)wptr;

    for (int it = 0; it < nIter; ++it) {
        __syncthreads();
        As[lcol + 0][lrow] = av.x; As[lcol + 1][lrow] = av.y;
        As[lcol + 2][lrow] = av.z; As[lcol + 3][lrow] = av.w;
        Ws[lcol + 0][lrow] = wv.x; Ws[lcol + 1][lrow] = wv.y;
        Ws[lcol + 2][lrow] = wv.z; Ws[lcol + 3][lrow] = wv.w;
        __syncthreads();
        if (it < nIter - 1) {
            av = *(const float4*)(aptr + (it + 1) * BK);
            if (MUL) { const float4 rv = *(const float4*)(rptr + (it + 1) * BK);
                       av.x *= rv.x; av.y *= rv.y; av.z *= rv.z; av.w *= rv.w; }
            wv = *(const float4*)(wptr + (it + 1) * BK);
        }
        MAC_LOOP();
    }
    #pragma unroll
    for (int i = 0; i < 4; ++i) {
        const int m = bm + (ty << 2) + i;
        #pragma unroll
        for (int j = 0; j < 4; ++j)
            p[m * 512 + bn + (tx << 2) + j] = acc[i][j];
    }
}

// All input-only GEMM parts in one launch. z 0..5: d splits (K=1536) ->
// dbase slices 0..5 (hc1 dead space); z 6..13: r (0..3) / z (4..7) -> rzbase.
__global__ __launch_bounds__(256) void k_gemm_drz(
    const float* __restrict__ sample, const float* __restrict__ hidden,
    const float* __restrict__ d0,
    const float* __restrict__ Wd, const float* __restrict__ Wr,
    const float* __restrict__ Wz,
    float* __restrict__ dbase, float* __restrict__ rzbase)
{
    __shared__ float As[BK][BM + 4];
    __shared__ float Ws[BK][BN + 4];
    const int z = blockIdx.z;
    if (z < 6) {
        const int ks = z << 8, seg = ks >> 9;
        const float* ab = (seg == 0 ? sample : (seg == 1 ? hidden : d0)) + (ks & 511);
        gemm64<false>(As, Ws, ab, nullptr, Wd, 1536, ks,
                      blockIdx.y * BM, blockIdx.x * BN, 16, dbase + (size_t)z * BH);
    } else {
        const int id = z - 6, gz = id >> 2, s = id & 3, ks = s << 8;
        const float* ab = (ks < 512 ? sample + ks : hidden + (ks - 512));
        gemm64<false>(As, Ws, ab, nullptr, gz ? Wz : Wr, 1024, ks,
                      blockIdx.y * BM, blockIdx.x * BN, 16, rzbase + (size_t)id * BH);
    }
}

// dv/rb/zb reduce: consumes d-parts (hc1 slices 0..5, dead afterwards) and
// r/z parts (ws 0..7, dead afterwards -> reused for h-parts and accs).
__global__ __launch_bounds__(256) void k_dv(
    const float4* __restrict__ dparts, const float4* __restrict__ bd,
    const float4* __restrict__ rzparts, const float4* __restrict__ br,
    const float4* __restrict__ bz,
    float4* __restrict__ dv4, float4* __restrict__ rb4, float4* __restrict__ zb4)
{
    const int g = blockIdx.x * 256 + threadIdx.x;
    const int n = g & (H4 - 1);
    float4 sd = bd[n], sr = br[n], sz = bz[n];
    #pragma unroll
    for (int s = 0; s < 6; ++s) { const float4 p = dparts[(size_t)s * BH4 + g];
        sd.x += p.x; sd.y += p.y; sd.z += p.z; sd.w += p.w; }
    #pragma unroll
    for (int s = 0; s < 4; ++s) { const float4 p = rzparts[(size_t)s * BH4 + g];
        sr.x += p.x; sr.y += p.y; sr.z += p.z; sr.w += p.w; }
    #pragma unroll
    for (int s = 4; s < 8; ++s) { const float4 p = rzparts[(size_t)s * BH4 + g];
        sz.x += p.x; sz.y += p.y; sz.z += p.z; sz.w += p.w; }
    const float4 d = sig4(sd);
    dv4[g] = make_float4(0.5f * d.x, 0.5f * d.y, 0.5f * d.z, 0.5f * d.w);
    rb4[g] = sig4(sr);
    zb4[g] = sig4(sz);
}

// ---------------------------------------------------------------------------
// mega: blocks 0..127 = h-GEMM (-> ws slices 0..3);
//       blocks 128..1151 = filter, 8 K-segments x 128 blocks (4 blocks/CU),
// batch-8 double-buffered float4, nontemporal stores for the hc1 stream.
// Segment s: t = 32s..32s+31, k = 255-t, local cumprod from 1;
// acc_s -> ws slice (s<4 ? 4+s : 6+s). The k=0 store lands one slice BELOW
// hc1 (= out_hn region, overwritten by k_finalize) -> branch-free.
// ---------------------------------------------------------------------------
#define FLOADB(buf, b)                                                     \
    _Pragma("unroll")                                                      \
    for (int u = 0; u < 8; ++u)                                            \
        buf[u] = ld_base[-(ptrdiff_t)((b) * 8 + u) * BH4];

#define FCSTORE(buf, b)                                                    \
    _Pragma("unroll")                                                      \
    for (int u = 0; u < 8; ++u) {                                          \
        const int t = t0 + (b) * 8 + u;                                    \
        const float iv = s_inv[t], tv = s_tinv[t];                         \
        c.x *= fmaf(-d.x, iv, tv); c.y *= fmaf(-d.y, iv, tv);              \
        c.z *= fmaf(-d.z, iv, tv); c.w *= fmaf(-d.w, iv, tv);              \
        a.x = fmaf(buf[u].x, c.x, a.x); a.y = fmaf(buf[u].y, c.y, a.y);    \
        a.z = fmaf(buf[u].z, c.z, a.z); a.w = fmaf(buf[u].w, c.w, a.w);    \
        __builtin_nontemporal_store(*(const nf4*)&buf[u],                  \
            (nf4*)(st_base - (ptrdiff_t)((b) * 8 + u) * BH4));             \
    }

__global__ __launch_bounds__(256, 4) void k_mega(
    const float4* __restrict__ ht4, const float4* __restrict__ dv4,
    const float* __restrict__ sample, const float* __restrict__ hidden,
    const float* __restrict__ rb, const float* __restrict__ Wh,
    float* __restrict__ ws, float4* __restrict__ hc14)
{
    if (blockIdx.x < 128) {
        __shared__ float As[BK][BM + 4];
        __shared__ float Wsh[BK][BN + 4];
        const int id = blockIdx.x;
        const int s = id >> 5, t2 = id & 31;
        const int bn = (t2 >> 2) << 6, bm = (t2 & 3) << 6, ks = s << 8;
        if (ks < 512)
            gemm64<false>(As, Wsh, sample + ks, nullptr, Wh, 1024, ks, bm, bn, 16,
                          ws + (size_t)s * BH);
        else
            gemm64<true>(As, Wsh, hidden + (ks - 512), rb + (ks - 512), Wh, 1024, ks,
                         bm, bn, 16, ws + (size_t)s * BH);
        return;
    }
    __shared__ float s_inv[KF], s_tinv[KF];
    const int tid = threadIdx.x;
    const float fi = 1.0f / (float)(tid + 1);
    s_inv[tid] = fi; s_tinv[tid] = (float)tid * fi;
    __syncthreads();

    const int fb  = blockIdx.x - 128;                // 0..1023
    const int seg = fb >> 7;                         // 0..7
    const int q   = ((fb & 127) << 8) | tid;         // float4-column 0..32767
    const float4 d = dv4[q];
    const int t0 = seg << 5;

    const float4* ld_base = ht4 + (size_t)(255 - t0) * BH4 + q;
    float4*       st_base = hc14 + (ptrdiff_t)(254 - t0) * BH4 + q;

    float4 c = make_float4(1.f, 1.f, 1.f, 1.f);
    float4 a = make_float4(0.f, 0.f, 0.f, 0.f);

    float4 va[8], vb[8];
    FLOADB(va, 0);
    FLOADB(vb, 1);
    FCSTORE(va, 0);
    FLOADB(va, 2);
    FCSTORE(vb, 1);
    FLOADB(vb, 3);
    FCSTORE(va, 2);
    FCSTORE(vb, 3);

    const int slice = (seg < 4) ? (4 + seg) : (6 + seg);   // 4..7, 10..13
    ((float4*)ws)[(size_t)slice * BH4 + q] = a;
}

// finalize: recompute 7 segment-prefix products from dv (224-step chain),
// combine 8 segment accs, h-parts reduce, hn = tanh(.)*(1-z) - acc.
__global__ __launch_bounds__(256) void k_finalize(
    const float4* __restrict__ dv4, const float4* __restrict__ ws4,
    const float4* __restrict__ bh, const float4* __restrict__ zb4,
    float4* hc1_4, float4* __restrict__ hn_out)
{
    __shared__ float s_inv[224], s_tinv[224];
    const int tid = threadIdx.x;
    if (tid < 224) { const float fi = 1.0f / (float)(tid + 1);
                     s_inv[tid] = fi; s_tinv[tid] = (float)tid * fi; }
    __syncthreads();

    const int g = blockIdx.x * 256 + tid;
    const int n = g & (H4 - 1);
    const float4 d = dv4[g];

    float4 acc = ws4[(size_t)4 * BH4 + g];           // segment 0 acc
    float4 c = make_float4(1.f, 1.f, 1.f, 1.f);
    #pragma unroll
    for (int sgm = 1; sgm < 8; ++sgm) {
        #pragma unroll
        for (int t = (sgm - 1) * 32; t < sgm * 32; ++t) {
            const float iv = s_inv[t], tv = s_tinv[t];
            c.x *= fmaf(-d.x, iv, tv); c.y *= fmaf(-d.y, iv, tv);
            c.z *= fmaf(-d.z, iv, tv); c.w *= fmaf(-d.w, iv, tv);
        }
        const int sl = (sgm < 4) ? (4 + sgm) : (6 + sgm);
        const float4 ai = ws4[(size_t)sl * BH4 + g];
        acc.x = fmaf(c.x, ai.x, acc.x); acc.y = fmaf(c.y, ai.y, acc.y);
        acc.z = fmaf(c.z, ai.z, acc.z); acc.w = fmaf(c.w, ai.w, acc.w);
    }

    float4 hs = bh[n];
    #pragma unroll
    for (int s = 0; s < 4; ++s) { const float4 p = ws4[(size_t)s * BH4 + g];
        hs.x += p.x; hs.y += p.y; hs.z += p.z; hs.w += p.w; }
    const float4 z = zb4[g];

    float4 hn;
    hn.x = tanh_fast(hs.x) * (1.0f - z.x) - acc.x;
    hn.y = tanh_fast(hs.y) * (1.0f - z.y) - acc.y;
    hn.z = tanh_fast(hs.z) * (1.0f - z.z) - acc.z;
    hn.w = tanh_fast(hs.w) * (1.0f - z.w) - acc.w;
    hn_out[g] = hn;
    hc1_4[(size_t)255 * BH4 + g] = hn;
}

__global__ __launch_bounds__(256) void k_gemm_o(
    const float* __restrict__ hn, const float* __restrict__ Wo,
    float* __restrict__ parts, int chunk)
{
    __shared__ float As[BK][BM + 4];
    __shared__ float Ws[BK][BN + 4];
    const int s = blockIdx.z, ks = s * chunk;
    gemm64<false>(As, Ws, hn + ks, nullptr, Wo, 512, ks,
                  blockIdx.y * BM, blockIdx.x * BN, chunk / BK, parts + (size_t)s * BH);
}

// no __restrict__: fallback path calls with parts == out (same-thread RMW)
__global__ __launch_bounds__(256) void k_reduce_o(
    const float4* parts, const float4* __restrict__ bo, float4* out, int NS)
{
    const int g = blockIdx.x * 256 + threadIdx.x;
    float4 v = bo[g & (H4 - 1)];
    for (int s = 0; s < NS; ++s) { const float4 p = parts[(size_t)s * BH4 + g];
        v.x += p.x; v.y += p.y; v.z += p.z; v.w += p.w; }
    out[g] = v;
}

// ------------------------- fallback-only kernels ---------------------------
__global__ __launch_bounds__(256) void k_reduce_rz(
    const float4* __restrict__ parts, const float4* __restrict__ br,
    const float4* __restrict__ bz, float4* __restrict__ rb, float4* __restrict__ zb)
{
    const int g = blockIdx.x * 256 + threadIdx.x;
    const int n = g & (H4 - 1);
    float4 r = br[n], z = bz[n];
    #pragma unroll
    for (int s = 0; s < 4; ++s) { const float4 p = parts[(size_t)s * BH4 + g];
        r.x += p.x; r.y += p.y; r.z += p.z; r.w += p.w; }
    #pragma unroll
    for (int s = 4; s < 8; ++s) { const float4 p = parts[(size_t)s * BH4 + g];
        z.x += p.x; z.y += p.y; z.z += p.z; z.w += p.w; }
    rb[g] = sig4(r); zb[g] = sig4(z);
}

__global__ __launch_bounds__(256) void k_gemm_h(
    const float* __restrict__ sample, const float* __restrict__ hidden,
    const float* __restrict__ rb, const float* __restrict__ Wh,
    float* __restrict__ parts)
{
    __shared__ float As[BK][BM + 4];
    __shared__ float Ws[BK][BN + 4];
    const int s = blockIdx.z, ks = s << 8;
    if (ks < 512)
        gemm64<false>(As, Ws, sample + ks, nullptr, Wh, 1024, ks,
                      blockIdx.y * BM, blockIdx.x * BN, 16, parts + (size_t)s * BH);
    else
        gemm64<true>(As, Ws, hidden + (ks - 512), rb + (ks - 512), Wh, 1024, ks,
                     blockIdx.y * BM, blockIdx.x * BN, 16, parts + (size_t)s * BH);
}

__global__ __launch_bounds__(256) void k_filter_full(
    const float* __restrict__ ht, const float* dparts, const float* __restrict__ bd,
    const float* zbuf, const float* hparts, const float* __restrict__ bh,
    float* hc1, float* __restrict__ dv_out, float* __restrict__ hn_out)
{
    __shared__ float s_inv[KF], s_tinv[KF];
    const int tid = threadIdx.x;
    const float fi = 1.0f / (float)(tid + 1);
    s_inv[tid] = fi; s_tinv[tid] = (float)tid * fi;
    __syncthreads();

    const int g = blockIdx.x * 256 + tid;
    const int n = g & (H_ - 1);
    float sd = bd[n];
    #pragma unroll
    for (int s = 0; s < 6; ++s) sd += dparts[(size_t)s * BH + g];
    const float d = 0.5f * sigmoidf_(sd);
    dv_out[g] = d;
    float sh = bh[n];
    #pragma unroll
    for (int s = 0; s < 4; ++s) sh += hparts[(size_t)s * BH + g];
    const float z = zbuf[g];

    float c = 1.0f, acc = 0.0f;
    #pragma unroll 16
    for (int t = 0; t < KF; ++t) {
        const int k = KF - 1 - t;
        const float v = ht[(size_t)k * BH + g];
        c *= fmaf(-d, s_inv[t], s_tinv[t]);
        acc = fmaf(v, c, acc);
        if (k >= 1) hc1[(size_t)(k - 1) * BH + g] = v;
    }
    const float hn = tanh_fast(sh) * (1.0f - z) - acc;
    hc1[(size_t)(KF - 1) * BH + g] = hn;
    hn_out[g] = hn;
}

extern "C" void kernel_launch(void* const* d_in, const int* in_sizes, int n_in,
                              void* d_out, int out_size, void* d_ws, size_t ws_size,
                              hipStream_t stream)
{
    const float* sample = (const float*)d_in[0];
    const float* hidden = (const float*)d_in[1];
    const float* ht     = (const float*)d_in[2];
    const float* d0     = (const float*)d_in[3];
    const float* Wd = (const float*)d_in[4];
    const float* bd = (const float*)d_in[5];
    const float* Wr = (const float*)d_in[6];
    const float* br = (const float*)d_in[7];
    const float* Wz = (const float*)d_in[8];
    const float* bz = (const float*)d_in[9];
    const float* Wh = (const float*)d_in[10];
    const float* bh = (const float*)d_in[11];
    const float* Wo = (const float*)d_in[12];
    const float* bo = (const float*)d_in[13];

    float* out     = (float*)d_out;
    float* out_o   = out;
    float* out_hn  = out + BH;
    float* out_hc1 = out + 2 * BH;
    float* out_dv  = out + 2 * BH + (size_t)KF * BH;

    const size_t slice = BH;
    const size_t need = 14ull * slice * sizeof(float);

    if (ws_size >= need) {
        float* ws = (float*)d_ws;
        // ws slices: [0..3] r-parts -> h-parts -> o-parts
        //            [4..7] z-parts -> filter accs 0..3
        //            [8] rb, [9] zb, [10..13] filter accs 4..7
        // d-parts -> hc1 slices 0..5 (dead after k_dv, overwritten by filter).
        float* rb = ws + 8 * slice;
        float* zb = ws + 9 * slice;

        k_gemm_drz<<<dim3(8, 4, 14), 256, 0, stream>>>(sample, hidden, d0,
                                                       Wd, Wr, Wz, out_hc1, ws);
        k_dv<<<dim3(128), 256, 0, stream>>>(
            (const float4*)out_hc1, (const float4*)bd,
            (const float4*)ws, (const float4*)br, (const float4*)bz,
            (float4*)out_dv, (float4*)rb, (float4*)zb);
        k_mega<<<dim3(1152), 256, 0, stream>>>(
            (const float4*)ht, (const float4*)out_dv, sample, hidden, rb, Wh,
            ws, (float4*)out_hc1);
        k_finalize<<<dim3(128), 256, 0, stream>>>(
            (const float4*)out_dv, (const float4*)ws,
            (const float4*)bh, (const float4*)zb,
            (float4*)out_hc1, (float4*)out_hn);
        k_gemm_o<<<dim3(8, 4, 4), 256, 0, stream>>>(out_hn, Wo, ws, 128);
        k_reduce_o<<<dim3(128), 256, 0, stream>>>((const float4*)ws,
                                                  (const float4*)bo,
                                                  (float4*)out_o, 4);
    } else {
        // serial fallback, all scratch = dead hc1 slices
        float* sl = out_hc1;
        k_gemm_drz<<<dim3(8, 4, 14), 256, 0, stream>>>(sample, hidden, d0,
                                                       Wd, Wr, Wz, sl, sl + 6 * slice);
        k_reduce_rz<<<dim3(128), 256, 0, stream>>>((const float4*)(sl + 6 * slice),
                                                   (const float4*)br, (const float4*)bz,
                                                   (float4*)(sl + 14 * slice),
                                                   (float4*)(sl + 15 * slice));
        k_gemm_h<<<dim3(8, 4, 4), 256, 0, stream>>>(sample, hidden, sl + 14 * slice, Wh,
                                                    sl + 16 * slice);
        k_filter_full<<<dim3(512), 256, 0, stream>>>(ht, sl, bd, sl + 15 * slice,
                                                     sl + 16 * slice, bh,
                                                     out_hc1, out_dv, out_hn);
        k_gemm_o<<<dim3(8, 4, 1), 256, 0, stream>>>(out_hn, Wo, out_o, 512);
        k_reduce_o<<<dim3(128), 256, 0, stream>>>((const float4*)out_o, (const float4*)bo,
                                                  (float4*)out_o, 1);
    }
}